// Round 3
// baseline (10837.829 us; speedup 1.0000x reference)
//
#include <hip/hip_runtime.h>

// InverseRecurrentLayer: 512-step scan  state = tanh(inputs[:,t,:]@R + state@Wt + bias)
// Wt alternates every 64 steps between inv(W) (== W^T, W orthogonal) and W.
// Persistent kernel, 64 blocks x 256 threads, hand-rolled grid barrier per step.
// v3: NO agent fences (they bulk-wbl2/inv the whole per-XCD L2 every step -> 15us/step).
// State exchange via fine-grained sc1 atomics (relaxed, agent scope) at MALL;
// read-only data (inputs/W/R) stays L2-cached. 2-deep pipelined state loads.

#define NBLK 64
#define NTHR 256
#define TSTEPS 512

typedef __attribute__((ext_vector_type(4))) float f32x4;
typedef __attribute__((ext_vector_type(8))) __bf16 bf16x8;
typedef unsigned long long u64;

__device__ __forceinline__ f32x4 mfma16(bf16x8 a, bf16x8 b, f32x4 c){
  return __builtin_amdgcn_mfma_f32_16x16x32_bf16(a, b, c, 0, 0, 0);
}
__device__ __forceinline__ unsigned bfbits(__bf16 h){
  union{__bf16 b; unsigned short u;} x; x.b = h; return (unsigned)x.u;
}

// grid barrier WITHOUT L2 fences: syncthreads (drains vmcnt per wave) -> flag -> poll
__device__ __forceinline__ void gbar(unsigned* flags, unsigned gen){
  __syncthreads();                       // hipcc emits s_waitcnt vmcnt(0) before s_barrier
  if (threadIdx.x == 0)
    __hip_atomic_store(flags + blockIdx.x, gen, __ATOMIC_RELAXED, __HIP_MEMORY_SCOPE_AGENT);
  if (threadIdx.x < 64){
    for (;;){
      unsigned v = __hip_atomic_load(flags + threadIdx.x, __ATOMIC_RELAXED, __HIP_MEMORY_SCOPE_AGENT);
      if (__all((int)(v >= gen))) break;
      __builtin_amdgcn_s_sleep(1);
    }
  }
  __syncthreads();
}

// input-projection partials for step t: accin[m] += bf16(inputs[b,t,fq..fq+128]) @ rb
__device__ __forceinline__ void input_accum(f32x4 (&accin)[4], const float* __restrict__ inputs,
                                            const bf16x8 (&rb)[4], int t, int fq, int lr, int lg){
  #pragma unroll
  for (int kb = 0; kb < 4; ++kb){
    #pragma unroll
    for (int m = 0; m < 4; ++m){
      const float* ip = inputs + ((size_t)(m*16 + lr) * 512 + (size_t)t) * 512 + fq + kb*32 + lg*8;
      float4 xa = *(const float4*)ip;
      float4 xb = *(const float4*)(ip + 4);
      bf16x8 a;
      a[0] = (__bf16)xa.x; a[1] = (__bf16)xa.y; a[2] = (__bf16)xa.z; a[3] = (__bf16)xa.w;
      a[4] = (__bf16)xb.x; a[5] = (__bf16)xb.y; a[6] = (__bf16)xb.z; a[7] = (__bf16)xb.w;
      accin[m] = mfma16(a, rb[kb], accin[m]);
    }
  }
}

// ---- pipelined state loads: group = one kb (32 k) for all 4 row-blocks ----
__device__ __forceinline__ void load_grp(const u64* sh64, const u64* sl64,
                                         int kb, int kq, int lr, int lg,
                                         u64 (&H)[4][2], u64 (&L)[4][2]){
  const int koff = kq + kb*32 + lg*8;
  #pragma unroll
  for (int m = 0; m < 4; ++m){
    const int base = (m*16 + lr)*256 + (koff >> 2);   // u64 index into [64][256]
    H[m][0] = __hip_atomic_load(sh64 + base,     __ATOMIC_RELAXED, __HIP_MEMORY_SCOPE_AGENT);
    H[m][1] = __hip_atomic_load(sh64 + base + 1, __ATOMIC_RELAXED, __HIP_MEMORY_SCOPE_AGENT);
    L[m][0] = __hip_atomic_load(sl64 + base,     __ATOMIC_RELAXED, __HIP_MEMORY_SCOPE_AGENT);
    L[m][1] = __hip_atomic_load(sl64 + base + 1, __ATOMIC_RELAXED, __HIP_MEMORY_SCOPE_AGENT);
  }
}
__device__ __forceinline__ void comp_grp(f32x4 (&acc)[4], const u64 (&H)[4][2], const u64 (&L)[4][2],
                                         const char* ldsPhi, const char* ldsPlo,
                                         int kb, int kq, int lr, int lg){
  const int koff = kq + kb*32 + lg*8;
  const int lb = lr * 2048 + (((unsigned)(koff << 1)) ^ ((lr & 7) << 4));
  bf16x8 bh = *(const bf16x8*)(ldsPhi + lb);
  bf16x8 bl = *(const bf16x8*)(ldsPlo + lb);
  #pragma unroll
  for (int m = 0; m < 4; ++m){
    union{u64 q[2]; bf16x8 v;} ah, al;
    ah.q[0] = H[m][0]; ah.q[1] = H[m][1];
    al.q[0] = L[m][0]; al.q[1] = L[m][1];
    acc[m] = mfma16(ah.v, bh, acc[m]);
    acc[m] = mfma16(ah.v, bl, acc[m]);
    acc[m] = mfma16(al.v, bh, acc[m]);
  }
}

__global__ __launch_bounds__(NTHR, 1) void irl_scan(
    const float* __restrict__ inputs, const float* __restrict__ R,
    const float* __restrict__ W, const float* __restrict__ bias,
    const float* __restrict__ x0, float* __restrict__ out,
    unsigned* __restrict__ st_hi32, unsigned* __restrict__ st_lo32,
    unsigned* __restrict__ flags)
{
  __shared__ char ldsPhi[16 * 2048];           // W-slice hi, XOR-swizzled
  __shared__ char ldsPlo[16 * 2048];           // W-slice lo
  __shared__ __attribute__((aligned(16))) float red2[4][4][16][24];

  const int tid = threadIdx.x;
  const int w  = tid >> 6;      // wave: K-quarter owner, epilogue row-block owner
  const int l  = tid & 63;
  const int lr = l & 15;        // A row in 16-block / B col / D col
  const int lg = l >> 4;        // k-group / D row-subgroup
  const int col0 = blockIdx.x << 4;
  const int u = col0 + lr;
  const float bias_c = bias[u];
  const int kq = w << 8;        // recurrent K base (256/wave)
  const int fq = w << 7;        // input-proj K base (128/wave)

  // R^T B-fragments in registers (time-invariant)
  bf16x8 rb[4];
  #pragma unroll
  for (int kb = 0; kb < 4; ++kb){
    bf16x8 t;
    #pragma unroll
    for (int j = 0; j < 8; ++j)
      t[j] = (__bf16)R[(size_t)(fq + kb*32 + lg*8 + j) * 1024 + u];
    rb[kb] = t;
  }

  // state[0] <- x0 : pack col-pairs into u32, sc1 atomic stores
  for (int i = tid; i < 64 * 8; i += NTHR){
    int b = i >> 3, cp = i & 7;
    float v0 = x0[col0 + 2*cp], v1 = x0[col0 + 2*cp + 1];
    __bf16 h0 = (__bf16)v0, h1 = (__bf16)v1;
    __bf16 l0 = (__bf16)(v0 - (float)h0), l1 = (__bf16)(v1 - (float)h1);
    int idx = b*512 + (col0 >> 1) + cp;
    __hip_atomic_store(st_hi32 + idx, bfbits(h0) | (bfbits(h1) << 16), __ATOMIC_RELAXED, __HIP_MEMORY_SCOPE_AGENT);
    __hip_atomic_store(st_lo32 + idx, bfbits(l0) | (bfbits(l1) << 16), __ATOMIC_RELAXED, __HIP_MEMORY_SCOPE_AGENT);
  }

  // input partials for t=0 (read-only data, safe before barrier)
  f32x4 zero = {0.f, 0.f, 0.f, 0.f};
  f32x4 accin[4];
  #pragma unroll
  for (int m = 0; m < 4; ++m) accin[m] = zero;
  input_accum(accin, inputs, rb, 0, fq, lr, lg);

  gbar(flags, 1u);

  unsigned cur = 0;
  int pp = -1;
  for (int t = 0; t < TSTEPS; ++t){
    const int ph = (t >> 6) & 1;    // 1 -> W, 0 -> inv(W)=W^T
    if (ph != pp){
      for (int i = tid; i < 16 * 1024; i += NTHR){
        int n = i >> 10, k = i & 1023;
        float v = ph ? W[(size_t)k * 1024 + col0 + n]
                     : W[(size_t)(col0 + n) * 1024 + k];
        __bf16 hi = (__bf16)v;
        __bf16 lo = (__bf16)(v - (float)hi);
        int off = n * 2048 + (((unsigned)(k << 1)) ^ ((n & 7) << 4));
        *(__bf16*)(ldsPhi + off) = hi;
        *(__bf16*)(ldsPlo + off) = lo;
      }
      pp = ph;
      __syncthreads();
    }

    const u64* sh64 = (const u64*)(st_hi32 + ((size_t)cur << 15));
    const u64* sl64 = (const u64*)(st_lo32 + ((size_t)cur << 15));

    f32x4 acc[4];
    #pragma unroll
    for (int m = 0; m < 4; ++m) acc[m] = accin[m];

    // 2-deep pipelined split-bf16 recurrent GEMM over this wave's K-quarter
    u64 HA[4][2], LA[4][2], HB[4][2], LB[4][2];
    load_grp(sh64, sl64, 0, kq, lr, lg, HA, LA);
    #pragma unroll
    for (int kb = 0; kb < 8; ++kb){
      if (kb & 1){
        if (kb < 7) load_grp(sh64, sl64, kb + 1, kq, lr, lg, HA, LA);
        comp_grp(acc, HB, LB, ldsPhi, ldsPlo, kb, kq, lr, lg);
      } else {
        if (kb < 7) load_grp(sh64, sl64, kb + 1, kq, lr, lg, HB, LB);
        comp_grp(acc, HA, LA, ldsPhi, ldsPlo, kb, kq, lr, lg);
      }
    }

    // cross-wave K reduction via LDS
    #pragma unroll
    for (int m = 0; m < 4; ++m)
      *(f32x4*)&red2[w][m][lr][lg * 4] = acc[m];
    __syncthreads();

    f32x4 s = *(const f32x4*)&red2[0][w][lr][lg * 4];
    s = s + *(const f32x4*)&red2[1][w][lr][lg * 4];
    s = s + *(const f32x4*)&red2[2][w][lr][lg * 4];
    s = s + *(const f32x4*)&red2[3][w][lr][lg * 4];

    // epilogue: wave w owns rows 16w..16w+15, row = 16w + lg*4 + j
    unsigned* nh = st_hi32 + ((size_t)(cur ^ 1u) << 15);
    unsigned* nl = st_lo32 + ((size_t)(cur ^ 1u) << 15);
    float* outp = out + (size_t)t * 65536 + (size_t)(w*16 + lg*4) * 1024 + u;
    #pragma unroll
    for (int j = 0; j < 4; ++j){
      float v = tanhf(s[j] + bias_c);
      outp[j * 1024] = v;
      __bf16 hi = (__bf16)v;
      __bf16 lo = (__bf16)(v - (float)hi);
      const int b = w*16 + lg*4 + j;
      unsigned myhi = bfbits(hi), mylo = bfbits(lo);
      unsigned phi = (unsigned)__shfl_xor((int)myhi, 1);
      unsigned plo = (unsigned)__shfl_xor((int)mylo, 1);
      const int idx = b*512 + ((col0 + lr) >> 1);
      if ((lr & 1) == 0)
        __hip_atomic_store(nh + idx, myhi | (phi << 16), __ATOMIC_RELAXED, __HIP_MEMORY_SCOPE_AGENT);
      else
        __hip_atomic_store(nl + idx, plo | (mylo << 16), __ATOMIC_RELAXED, __HIP_MEMORY_SCOPE_AGENT);
    }

    cur ^= 1u;
    if (t < TSTEPS - 1){
      // pre-accumulate next step's input projection BEFORE the barrier
      #pragma unroll
      for (int m = 0; m < 4; ++m) accin[m] = zero;
      input_accum(accin, inputs, rb, t + 1, fq, lr, lg);
      gbar(flags, (unsigned)(t + 2));
    }
  }
}

extern "C" void kernel_launch(void* const* d_in, const int* in_sizes, int n_in,
                              void* d_out, int out_size, void* d_ws, size_t ws_size,
                              hipStream_t stream){
  (void)in_sizes; (void)n_in; (void)out_size; (void)ws_size;
  const float* inputs = (const float*)d_in[0];   // [64,512,512] f32
  const float* R      = (const float*)d_in[1];   // [512,1024]  f32
  const float* W      = (const float*)d_in[2];   // [1024,1024] f32
  const float* bias   = (const float*)d_in[3];   // [1024]      f32
  const float* x0     = (const float*)d_in[4];   // [1024]      f32
  float* out = (float*)d_out;                    // [512,64,1024] f32

  char* ws = (char*)d_ws;
  unsigned* flags   = (unsigned*)ws;                        // 4KB
  unsigned* st_hi32 = (unsigned*)(ws + 4096);               // 2 x 64x512 u32 (bf16 col-pairs)
  unsigned* st_lo32 = (unsigned*)(ws + 4096 + 262144);      // 2 x 64x512 u32

  hipMemsetAsync(flags, 0, 4096, stream);
  hipLaunchKernelGGL(irl_scan, dim3(NBLK), dim3(NTHR), 0, stream,
                     inputs, R, W, bias, x0, out, st_hi32, st_lo32, flags);
}

// Round 4
// 6802.148 us; speedup vs baseline: 1.5933x; 1.5933x over previous
//
#include <hip/hip_runtime.h>

// InverseRecurrentLayer: 512-step scan  state = tanh(inputs[:,t,:]@R + state@Wt + bias)
// Wt alternates every 64 steps between inv(W) (== W^T, W orthogonal) and W.
// v4: latency-attack. 64 blocks x 1024 threads (16 waves -> 4 waves/SIMD TLP).
// fp16 single-pass MFMA (state is tanh-bounded; fp16 quant ~2^-11 -> ~3e-3 walk).
// No agent fences ever (L2 keeps inputs/W); state via relaxed agent atomics (MALL).
// Non-temporal out stores protect L2. W-slice fp16 LDS-resident, re-staged per phase.

#define NBLK 64
#define NTHR 1024
#define TSTEPS 512

typedef __attribute__((ext_vector_type(4))) float f32x4;
typedef __attribute__((ext_vector_type(8))) _Float16 f16x8;
typedef unsigned long long u64;
typedef unsigned int u32;

union frag2 { u64 q[2]; f16x8 v; };
union pk2   { _Float16 h[2]; u32 u; };

__device__ __forceinline__ f32x4 mfma16(f16x8 a, f16x8 b, f32x4 c){
  return __builtin_amdgcn_mfma_f32_16x16x32_f16(a, b, c, 0, 0, 0);
}

// grid barrier, NO L2 fences: __syncthreads drains vmcnt (stores committed to MALL
// since they are sc1 atomics), then flag store + 64-lane poll of 64 flags.
__device__ __forceinline__ void gbar(unsigned* flags, unsigned gen){
  __syncthreads();
  if (threadIdx.x == 0)
    __hip_atomic_store(flags + blockIdx.x, gen, __ATOMIC_RELAXED, __HIP_MEMORY_SCOPE_AGENT);
  if (threadIdx.x < 64){
    for (;;){
      unsigned v = __hip_atomic_load(flags + threadIdx.x, __ATOMIC_RELAXED, __HIP_MEMORY_SCOPE_AGENT);
      if (__all((int)(v >= gen))) break;
      __builtin_amdgcn_s_sleep(1);
    }
  }
  __syncthreads();
  asm volatile("" ::: "memory");   // compile-time fence: nothing drifts above the poll
}

// input-projection partials for step t (this wave's K=32 slice of F=512)
__device__ __forceinline__ void input_accum(f32x4 (&accin)[4], const float* __restrict__ inputs,
                                            f16x8 rb, int t, int fq, int lr, int lg){
  #pragma unroll
  for (int m = 0; m < 4; ++m){
    const float* ip = inputs + ((size_t)(m*16 + lr) * 512 + (size_t)t) * 512 + fq + lg*8;
    float4 xa = *(const float4*)ip;
    float4 xb = *(const float4*)(ip + 4);
    f16x8 a;
    a[0]=(_Float16)xa.x; a[1]=(_Float16)xa.y; a[2]=(_Float16)xa.z; a[3]=(_Float16)xa.w;
    a[4]=(_Float16)xb.x; a[5]=(_Float16)xb.y; a[6]=(_Float16)xb.z; a[7]=(_Float16)xb.w;
    accin[m] = mfma16(a, rb, accin[m]);
  }
}

__global__ __launch_bounds__(NTHR) void irl_scan(
    const float* __restrict__ inputs, const float* __restrict__ R,
    const float* __restrict__ W, const float* __restrict__ bias,
    const float* __restrict__ x0, float* __restrict__ out,
    unsigned short* __restrict__ st,   // 2 x [64][1024] fp16 state (ping-pong)
    unsigned* __restrict__ flags)
{
  __shared__ char  wlds[16 * 2048];    // fp16 W-slice [col][k], XOR-swizzled (32KB)
  __shared__ float red[16][64][16];    // 16 wave-partials of [64 rows][16 cols] (64KB)

  const int tid = threadIdx.x;
  const int w  = tid >> 6;       // wave 0..15 : K-chunk owner (64 k each)
  const int l  = tid & 63;
  const int lr = l & 15;         // A row in tile / B col
  const int lg = l >> 4;         // k-subgroup
  const int col0 = blockIdx.x << 4;
  const int kq = w << 6;         // recurrent K base (64/wave)
  const int fq = w << 5;         // input-proj K base (32/wave)
  const int orow = tid >> 4;     // reduce/epilogue: output row (batch)
  const int oc   = tid & 15;     // reduce/epilogue: output col
  const float bias_v = bias[col0 + oc];

  // R fragment (one per thread, time-invariant)
  f16x8 rb;
  #pragma unroll
  for (int j = 0; j < 8; ++j)
    rb[j] = (_Float16)R[(size_t)(fq + lg*8 + j) * 1024 + col0 + lr];

  // state[0] <- x0 (this block's 16 columns, all 64 rows), packed u32 stores
  if (tid < 512){
    int row = tid >> 3, cp = tid & 7;
    pk2 p;
    p.h[0] = (_Float16)x0[col0 + 2*cp];
    p.h[1] = (_Float16)x0[col0 + 2*cp + 1];
    __hip_atomic_store((u32*)st + row*512 + (col0 >> 1) + cp, p.u,
                       __ATOMIC_RELAXED, __HIP_MEMORY_SCOPE_AGENT);
  }

  f32x4 zero = {0.f, 0.f, 0.f, 0.f};
  f32x4 accin[4];
  #pragma unroll
  for (int m = 0; m < 4; ++m) accin[m] = zero;
  input_accum(accin, inputs, rb, 0, fq, lr, lg);

  gbar(flags, 1u);

  unsigned cur = 0;
  int pp = -1;
  for (int t = 0; t < TSTEPS; ++t){
    const int ph = (t >> 6) & 1;    // 1 -> W, 0 -> inv(W)=W^T
    if (ph != pp){
      // stage fp16 W slice: B[n][k] = Wt[k][col0+n], pair-packed u32 writes
      for (int i = tid; i < 16 * 512; i += NTHR){
        int n = i >> 9, kp = i & 511, k0 = kp * 2;
        pk2 p;
        p.h[0] = (_Float16)(ph ? W[(size_t)k0 * 1024 + col0 + n]
                               : W[(size_t)(col0 + n) * 1024 + k0]);
        p.h[1] = (_Float16)(ph ? W[(size_t)(k0 + 1) * 1024 + col0 + n]
                               : W[(size_t)(col0 + n) * 1024 + k0 + 1]);
        int byte = n * 2048 + (((u32)(k0 << 1)) ^ ((n & 7) << 4));
        *(u32*)(wlds + byte) = p.u;
      }
      pp = ph;
      __syncthreads();
    }

    const u64* sb = (const u64*)(st + ((size_t)cur << 16));

    // A-fragments: 4 row-tiles x 2 k-blocks, 16B each, relaxed agent atomics (MALL)
    frag2 fA[4][2];
    #pragma unroll
    for (int m = 0; m < 4; ++m){
      #pragma unroll
      for (int kb = 0; kb < 2; ++kb){
        const int koff = kq + kb*32 + lg*8;
        const u64* p = sb + ((size_t)(m*16 + lr) << 8) + (koff >> 2);
        fA[m][kb].q[0] = __hip_atomic_load(p,     __ATOMIC_RELAXED, __HIP_MEMORY_SCOPE_AGENT);
        fA[m][kb].q[1] = __hip_atomic_load(p + 1, __ATOMIC_RELAXED, __HIP_MEMORY_SCOPE_AGENT);
      }
    }

    f32x4 acc[4];
    #pragma unroll
    for (int m = 0; m < 4; ++m) acc[m] = accin[m];

    #pragma unroll
    for (int kb = 0; kb < 2; ++kb){
      const int koff = kq + kb*32 + lg*8;
      f16x8 b = *(const f16x8*)(wlds + lr*2048 + (((u32)(koff << 1)) ^ ((lr & 7) << 4)));
      #pragma unroll
      for (int m = 0; m < 4; ++m) acc[m] = mfma16(fA[m][kb].v, b, acc[m]);
    }

    // cross-wave K reduction: wave w writes its [64][16] partial
    #pragma unroll
    for (int m = 0; m < 4; ++m){
      #pragma unroll
      for (int j = 0; j < 4; ++j)
        red[w][m*16 + lg*4 + j][lr] = acc[m][j];
    }
    __syncthreads();

    float s = 0.f;
    #pragma unroll
    for (int ww = 0; ww < 16; ++ww) s += red[ww][orow][oc];

    const float v = tanhf(s + bias_v);
    __builtin_nontemporal_store(v, out + (size_t)t * 65536 + (size_t)orow * 1024 + col0 + oc);

    // pack fp16 col-pairs via shfl, one u32 atomic store per even thread
    pk2 me; me.h[0] = (_Float16)v; me.h[1] = (_Float16)0.f;
    u32 other = (u32)__shfl_xor((int)me.u, 1);
    if ((oc & 1) == 0){
      u32* nb = (u32*)(st + ((size_t)(cur ^ 1u) << 16));
      __hip_atomic_store(nb + orow*512 + (col0 >> 1) + (oc >> 1),
                         (me.u & 0xffffu) | (other << 16),
                         __ATOMIC_RELAXED, __HIP_MEMORY_SCOPE_AGENT);
    }

    cur ^= 1u;
    if (t < TSTEPS - 1){
      // pre-accumulate next step's input projection BEFORE the barrier
      #pragma unroll
      for (int m = 0; m < 4; ++m) accin[m] = zero;
      input_accum(accin, inputs, rb, t + 1, fq, lr, lg);
      gbar(flags, (unsigned)(t + 2));
    }
  }
}

extern "C" void kernel_launch(void* const* d_in, const int* in_sizes, int n_in,
                              void* d_out, int out_size, void* d_ws, size_t ws_size,
                              hipStream_t stream){
  (void)in_sizes; (void)n_in; (void)out_size; (void)ws_size;
  const float* inputs = (const float*)d_in[0];   // [64,512,512] f32
  const float* R      = (const float*)d_in[1];   // [512,1024]  f32
  const float* W      = (const float*)d_in[2];   // [1024,1024] f32
  const float* bias   = (const float*)d_in[3];   // [1024]      f32
  const float* x0     = (const float*)d_in[4];   // [1024]      f32
  float* out = (float*)d_out;                    // [512,64,1024] f32

  char* ws = (char*)d_ws;
  unsigned* flags = (unsigned*)ws;                       // 4KB
  unsigned short* st = (unsigned short*)(ws + 4096);     // 2 x 64x1024 fp16

  hipMemsetAsync(flags, 0, 4096, stream);
  hipLaunchKernelGGL(irl_scan, dim3(NBLK), dim3(NTHR), 0, stream,
                     inputs, R, W, bias, x0, out, st, flags);
}

// Round 6
// 3985.118 us; speedup vs baseline: 2.7196x; 1.7069x over previous
//
#include <hip/hip_runtime.h>

// InverseRecurrentLayer: 512-step scan  state = tanh(inputs[:,t,:]@R + state@Wt + bias)
// Wt alternates every 64 steps between inv(W) (== W^T, W orthogonal) and W.
// v6: communication-minimal tiling. Batch rows are independent -> grid = 4 row-groups
// (16 rows) x 16 col-splits (64 cols). Each block stages only its row-group's state
// (32KB, 4K atomic 8B ops) -> 256K ops/step total (was 1M; per-step time scales with
// agent-atomic op count). Independent 16-block barriers per row-group (r4-proven
// flag-array pattern; r5 ticket barrier flaked). W-slice + R-slice fully in registers.

#define NTHR 512
#define TSTEPS 512

typedef __attribute__((ext_vector_type(4))) float f32x4;
typedef __attribute__((ext_vector_type(8))) _Float16 f16x8;
typedef unsigned long long u64;
typedef unsigned int u32;

union pk2 { _Float16 h[2]; u32 u; };

__device__ __forceinline__ f32x4 mfma16(f16x8 a, f16x8 b, f32x4 c){
  return __builtin_amdgcn_mfma_f32_16x16x32_f16(a, b, c, 0, 0, 0);
}

// 16-block group barrier (r4-proven flag-array pattern, scoped to the row-group):
// thread 0 stores this block's flag; wave 0 polls the group's 16 flags.
__device__ __forceinline__ void gbar(unsigned* gflags, int cblk, unsigned gen){
  __syncthreads();                // drains vmcnt: state stores committed before flag
  if (threadIdx.x == 0)
    __hip_atomic_store(gflags + cblk, gen, __ATOMIC_RELAXED, __HIP_MEMORY_SCOPE_AGENT);
  if (threadIdx.x < 64){
    const int src = (threadIdx.x < 16) ? threadIdx.x : 0;
    for (;;){
      unsigned v = __hip_atomic_load(gflags + src, __ATOMIC_RELAXED, __HIP_MEMORY_SCOPE_AGENT);
      if (__all((int)(v >= gen))) break;
      __builtin_amdgcn_s_sleep(1);
    }
  }
  __syncthreads();
  asm volatile("" ::: "memory");
}

// input projection partial for step t: this wave's K=256 slice of F=512
__device__ __forceinline__ f32x4 input_accum(const float* __restrict__ inputs,
                                             const f16x8 (&rf)[8],
                                             int t, int r0, int kg, int lr, int lg){
  f32x4 acc = {0.f, 0.f, 0.f, 0.f};
  const float* base = inputs + ((size_t)(r0 + lr) * 512 + (size_t)t) * 512 + kg*256 + lg*8;
  #pragma unroll
  for (int i = 0; i < 8; ++i){
    float4 xa = *(const float4*)(base + i*32);
    float4 xb = *(const float4*)(base + i*32 + 4);
    f16x8 a;
    a[0]=(_Float16)xa.x; a[1]=(_Float16)xa.y; a[2]=(_Float16)xa.z; a[3]=(_Float16)xa.w;
    a[4]=(_Float16)xb.x; a[5]=(_Float16)xb.y; a[6]=(_Float16)xb.z; a[7]=(_Float16)xb.w;
    acc = mfma16(a, rf[i], acc);
  }
  return acc;
}

__global__ __launch_bounds__(NTHR) void irl_scan(
    const float* __restrict__ inputs, const float* __restrict__ R,
    const float* __restrict__ W, const float* __restrict__ bias,
    const float* __restrict__ x0, float* __restrict__ out,
    unsigned short* __restrict__ st,   // 2 x [64][1024] fp16 state (ping-pong)
    unsigned* __restrict__ flags)
{
  __shared__ char  alds[16 * 2048];   // row-group state [16 rows][1024 k] fp16, XOR-swizzled
  __shared__ float red[4][16][16];    // kg=1 partials: [n-tile][row][col]

  const int tid = threadIdx.x;
  const int w   = tid >> 6;          // 8 waves
  const int n   = w & 3;             // N-tile (16 cols each)
  const int kg  = w >> 2;            // K-half (512 each)
  const int l   = tid & 63;
  const int lr  = l & 15;            // A row in tile / B col / D col
  const int lg  = l >> 4;            // k-subgroup / D row-subgroup
  const int cblk = blockIdx.x & 15;  // col-split
  const int grp  = blockIdx.x >> 4;  // row-group
  const int col0 = cblk << 6;        // 64 unit-columns per block
  const int r0   = grp << 4;         // 16 batch rows per block
  const int u    = col0 + n*16 + lr; // this thread's output column
  const float bias_u = bias[u];
  unsigned* gflags = flags + grp*64; // 256B per group: no false sharing across groups

  // ---- W fragments, BOTH phases, in registers (1024x64 slice per block) ----
  // wave (n,kg) covers k in [kg*512, kg*512+512) for its 16 cols; 16 frags/phase.
  f16x8 wf0[16], wf1[16];            // wf0: inv(W)=W^T, wf1: W
  #pragma unroll
  for (int i = 0; i < 16; ++i){
    const int k = kg*512 + i*32 + lg*8;
    f16x8 t0, t1;
    #pragma unroll
    for (int j = 0; j < 8; ++j){
      t0[j] = (_Float16)W[(size_t)u*1024 + (k + j)];     // W^T: B[n][k] = W[u][k]
      t1[j] = (_Float16)W[(size_t)(k + j)*1024 + u];     // W:   B[n][k] = W[k][u]
    }
    wf0[i] = t0; wf1[i] = t1;
  }

  // ---- R fragments in registers (this wave's K=256 slice of F=512) ----
  f16x8 rf[8];
  #pragma unroll
  for (int i = 0; i < 8; ++i){
    const int f = kg*256 + i*32 + lg*8;
    f16x8 tv;
    #pragma unroll
    for (int j = 0; j < 8; ++j)
      tv[j] = (_Float16)R[(size_t)(f + j)*1024 + u];
    rf[i] = tv;
  }

  // ---- state[0] <- x0 : block's 16 rows x 64 cols, packed u32 atomic stores ----
  {
    const int row = tid >> 5, cp = tid & 31;     // 16 rows x 32 col-pairs = 512 threads
    pk2 p;
    p.h[0] = (_Float16)x0[col0 + 2*cp];
    p.h[1] = (_Float16)x0[col0 + 2*cp + 1];
    __hip_atomic_store((u32*)st + (size_t)(r0 + row)*512 + (col0 >> 1) + cp, p.u,
                       __ATOMIC_RELAXED, __HIP_MEMORY_SCOPE_AGENT);
  }

  f32x4 accin = input_accum(inputs, rf, 0, r0, kg, lr, lg);
  gbar(gflags, cblk, 1u);

  unsigned cur = 0;
  for (int t = 0; t < TSTEPS; ++t){
    const int ph = (t >> 6) & 1;     // 1 -> W, 0 -> inv(W)=W^T

    // ---- stage row-group state into LDS: 4096 x 8B atomic loads (8/thread) ----
    const u64* sb = (const u64*)(st + ((size_t)cur << 16));
    #pragma unroll
    for (int j = 0; j < 8; ++j){
      const int idx = tid + j*512;
      const int row = idx >> 8, kc = idx & 255;          // kc: 4-k chunk (8B)
      u64 q = __hip_atomic_load(sb + (size_t)(r0 + row)*256 + kc,
                                __ATOMIC_RELAXED, __HIP_MEMORY_SCOPE_AGENT);
      *(u64*)(alds + row*2048 + ((kc*8) ^ ((row & 7) << 4))) = q;
    }
    __syncthreads();

    // ---- recurrent GEMM: 16 MFMAs over this wave's K-half ----
    f32x4 acc = accin;
    const int kb0 = kg*1024 + lg*16;                     // byte base of k-slice
    if (ph){
      #pragma unroll
      for (int i = 0; i < 16; ++i){
        const int kb = kb0 + i*64;
        f16x8 a = *(const f16x8*)(alds + lr*2048 + (kb ^ ((lr & 7) << 4)));
        acc = mfma16(a, wf1[i], acc);
      }
    } else {
      #pragma unroll
      for (int i = 0; i < 16; ++i){
        const int kb = kb0 + i*64;
        f16x8 a = *(const f16x8*)(alds + lr*2048 + (kb ^ ((lr & 7) << 4)));
        acc = mfma16(a, wf0[i], acc);
      }
    }

    // ---- kg reduction (2-way) via LDS ----
    if (kg == 1){
      #pragma unroll
      for (int j = 0; j < 4; ++j)
        red[n][lg*4 + j][lr] = acc[j];
    }
    __syncthreads();

    if (kg == 0){
      unsigned* nb = (unsigned*)(st + ((size_t)(cur ^ 1u) << 16));
      #pragma unroll
      for (int j = 0; j < 4; ++j){
        const int row = lg*4 + j;
        const float v = tanhf(acc[j] + red[n][row][lr] + bias_u);
        __builtin_nontemporal_store(v, out + (size_t)t*65536 + (size_t)(r0 + row)*1024 + u);
        pk2 me; me.h[0] = (_Float16)v; me.h[1] = (_Float16)0.f;
        const u32 other = (u32)__shfl_xor((int)me.u, 1);
        if (!(lr & 1))
          __hip_atomic_store(nb + (size_t)(r0 + row)*512 + (u >> 1),
                             (me.u & 0xffffu) | (other << 16),
                             __ATOMIC_RELAXED, __HIP_MEMORY_SCOPE_AGENT);
      }
    }

    cur ^= 1u;
    if (t < TSTEPS - 1){
      // pre-accumulate next step's input projection BEFORE the barrier
      accin = input_accum(inputs, rf, t + 1, r0, kg, lr, lg);
      gbar(gflags, cblk, (unsigned)(t + 2));
    }
  }
}

extern "C" void kernel_launch(void* const* d_in, const int* in_sizes, int n_in,
                              void* d_out, int out_size, void* d_ws, size_t ws_size,
                              hipStream_t stream){
  (void)in_sizes; (void)n_in; (void)out_size; (void)ws_size;
  const float* inputs = (const float*)d_in[0];   // [64,512,512] f32
  const float* R      = (const float*)d_in[1];   // [512,1024]  f32
  const float* W      = (const float*)d_in[2];   // [1024,1024] f32
  const float* bias   = (const float*)d_in[3];   // [1024]      f32
  const float* x0     = (const float*)d_in[4];   // [1024]      f32
  float* out = (float*)d_out;                    // [512,64,1024] f32

  char* ws = (char*)d_ws;
  unsigned* flags = (unsigned*)ws;                       // 4KB (4 groups x 256B)
  unsigned short* st = (unsigned short*)(ws + 4096);     // 2 x 64x1024 fp16

  hipMemsetAsync(flags, 0, 4096, stream);
  hipLaunchKernelGGL(irl_scan, dim3(64), dim3(NTHR), 0, stream,
                     inputs, R, W, bias, x0, out, st, flags);
}